// Round 16
// baseline (241.379 us; speedup 1.0000x reference)
//
#include <hip/hip_runtime.h>
#include <hip/hip_bf16.h>
#include <stdint.h>

// MoE: B=4,S=2048,D=512,F=2048,E=8,K=2.  T = B*S = 8192 tokens.
#define TT 8192
#define DD 512
#define FF 2048
#define EE 8
#define MAXT 136   // max row-tiles at BM=128

typedef __attribute__((ext_vector_type(8))) short bf16x8;
typedef __attribute__((ext_vector_type(4))) float f32x4;

static __device__ __forceinline__ unsigned short f2b(float f) {
  union { __hip_bfloat16 b; unsigned short u; } cv;
  cv.b = __float2bfloat16(f);
  return cv.u;
}
static __device__ __forceinline__ float b2f(unsigned short u) {
  union { unsigned int i; float f; } cv;
  cv.i = ((unsigned int)u) << 16;
  return cv.f;
}

// async global->LDS, 16B per lane. LDS dest must be wave_base + lane*16.
static __device__ __forceinline__ void gload16(const void* g, void* l) {
  __builtin_amdgcn_global_load_lds(
      (const __attribute__((address_space(1))) unsigned int*)g,
      (__attribute__((address_space(3))) unsigned int*)l, 16, 0, 0);
}

#define VMCNT8  asm volatile("s_waitcnt vmcnt(8)" ::: "memory")
#define VMCNT4  asm volatile("s_waitcnt vmcnt(4)" ::: "memory")
#define VMCNT0  asm volatile("s_waitcnt vmcnt(0)" ::: "memory")
#define BARX    asm volatile("s_barrier" ::: "memory")

// ---------------- prep: gate logits (fp32) + x->bf16 --------------------
__launch_bounds__(256)
__global__ void k_prep(const float* __restrict__ x, const float* __restrict__ Wg,
                       unsigned short* __restrict__ xb,
                       int* __restrict__ te, float* __restrict__ tw) {
  int wid = threadIdx.x >> 6, lane = threadIdx.x & 63;
  int t = blockIdx.x * 4 + wid;
  const float* xr = x + (size_t)t * DD;
  unsigned short* xbr = xb + (size_t)t * DD;
  int d0 = lane * 8;

  float4 v0 = *(const float4*)(xr + d0);
  float4 v1 = *(const float4*)(xr + d0 + 4);
  ushort4 o0, o1;
  o0.x = f2b(v0.x); o0.y = f2b(v0.y); o0.z = f2b(v0.z); o0.w = f2b(v0.w);
  o1.x = f2b(v1.x); o1.y = f2b(v1.y); o1.z = f2b(v1.z); o1.w = f2b(v1.w);
  *(ushort4*)(xbr + d0) = o0;
  *(ushort4*)(xbr + d0 + 4) = o1;

  float xv[8] = {v0.x, v0.y, v0.z, v0.w, v1.x, v1.y, v1.z, v1.w};
  float acc[EE];
#pragma unroll
  for (int e = 0; e < EE; e++) acc[e] = 0.f;
#pragma unroll
  for (int j = 0; j < 8; j++) {
    const float* wg = Wg + (size_t)(d0 + j) * EE;
    float4 a = *(const float4*)wg;
    float4 b = *(const float4*)(wg + 4);
    acc[0] += xv[j] * a.x; acc[1] += xv[j] * a.y; acc[2] += xv[j] * a.z; acc[3] += xv[j] * a.w;
    acc[4] += xv[j] * b.x; acc[5] += xv[j] * b.y; acc[6] += xv[j] * b.z; acc[7] += xv[j] * b.w;
  }
#pragma unroll
  for (int e = 0; e < EE; e++)
    for (int o = 32; o; o >>= 1) acc[e] += __shfl_xor(acc[e], o);
  if (lane == 0) {
    int e1 = 0; float v1m = acc[0];
#pragma unroll
    for (int e = 1; e < EE; e++) if (acc[e] > v1m) { v1m = acc[e]; e1 = e; }
    int e2 = -1; float v2m = -INFINITY;
#pragma unroll
    for (int e = 0; e < EE; e++) if (e != e1 && acc[e] > v2m) { v2m = acc[e]; e2 = e; }
    float ex = __expf(v2m - v1m);
    float w1 = 1.f / (1.f + ex);
    float w2 = ex / (1.f + ex);
    te[t * 2] = e1; te[t * 2 + 1] = e2;
    tw[t * 2] = w1; tw[t * 2 + 1] = w2;
  }
}

// ------------- transpose+convert all weights, one launch (z=0..23) ----------
__global__ void k_tcvt_all(const float* __restrict__ W, const float* __restrict__ V,
                           const float* __restrict__ W2, unsigned short* __restrict__ Wt,
                           unsigned short* __restrict__ Vt, unsigned short* __restrict__ W2t) {
  __shared__ float tile[32][33];
  int z = blockIdx.y;
  const float* src; unsigned short* dst; int N, nbx;
  if (z < 16) {
    int e = z & 7;
    size_t base = (size_t)e * DD * FF;
    src = (z < 8 ? W : V) + base;
    dst = (z < 8 ? Wt : Vt) + base;
    N = FF; nbx = FF / 32;          // in [DD][FF] -> out [FF][DD]
  } else {
    int e = z - 16;
    size_t base = (size_t)e * DD * FF;
    src = W2 + base; dst = W2t + base;
    N = DD; nbx = DD / 32;          // in [FF][DD] -> out [DD][FF]
  }
  int M = (z < 16) ? DD : FF;
  int bx = blockIdx.x;
  int cb = (bx % nbx) * 32, rb = (bx / nbx) * 32;
  int tx = threadIdx.x, ty = threadIdx.y;
#pragma unroll
  for (int i = 0; i < 4; i++)
    tile[ty + i * 8][tx] = src[(size_t)(rb + ty + i * 8) * N + cb + tx];
  __syncthreads();
#pragma unroll
  for (int i = 0; i < 4; i++)
    dst[(size_t)(cb + ty + i * 8) * M + rb + tx] = f2b(tile[tx][ty + i * 8]);
}

// ---------------- routing: single-block deterministic counting sort --------
__launch_bounds__(1024)
__global__ void k_route(const int* __restrict__ te, const float* __restrict__ tw,
                        int* __restrict__ ctrl, int* __restrict__ perm,
                        float* __restrict__ pw, int* __restrict__ tileE,
                        int* __restrict__ tileRow, int* __restrict__ inv) {
  __shared__ int wsum[17][EE];
  __shared__ int ebase[EE];
  int tid = threadIdx.x;
  int lane = tid & 63, wid = tid >> 6;
  int myte[16]; float mytw[16];
  int c[EE];
#pragma unroll
  for (int e = 0; e < EE; e++) c[e] = 0;
  int s0 = tid * 16;
#pragma unroll
  for (int j = 0; j < 16; j++) {
    myte[j] = te[s0 + j];
    mytw[j] = tw[s0 + j];
#pragma unroll
    for (int e = 0; e < EE; e++) if (myte[j] == e) c[e]++;
  }
  int incl[EE];
#pragma unroll
  for (int e = 0; e < EE; e++) incl[e] = c[e];
  for (int off = 1; off < 64; off <<= 1) {
#pragma unroll
    for (int e = 0; e < EE; e++) {
      int v = __shfl_up(incl[e], off);
      if (lane >= off) incl[e] += v;
    }
  }
  if (lane == 63)
#pragma unroll
    for (int e = 0; e < EE; e++) wsum[wid][e] = incl[e];
  __syncthreads();
  if (tid < EE) {
    int s = 0;
    for (int w = 0; w < 16; w++) { int v = wsum[w][tid]; wsum[w][tid] = s; s += v; }
    wsum[16][tid] = s;
  }
  __syncthreads();
  if (tid == 0) {
    int s = 0, nt = 0;
    for (int e = 0; e < EE; e++) {
      int cnt = wsum[16][e];
      ebase[e] = s; ctrl[8 + e] = s; ctrl[e] = cnt;
      for (int i = 0; i < cnt; i += 128) { tileE[nt] = e; tileRow[nt] = s + i; nt++; }
      s += cnt;
    }
    ctrl[16] = s; ctrl[17] = nt;
  }
  __syncthreads();
#pragma unroll
  for (int e = 0; e < EE; e++) {
    int p = ebase[e] + wsum[wid][e] + incl[e] - c[e];
#pragma unroll
    for (int j = 0; j < 16; j++) {
      if (myte[j] == e) {
        perm[p] = (s0 + j) >> 1;
        pw[p] = mytw[j];
        inv[s0 + j] = p;
        p++;
      }
    }
  }
}

// ---------------- GEMM1: h[pos][f] = pw * silu(x@W) * (x@V) -----------------
// BM=128 rows x 64 f-cols (W and V -> 128 LDS B-rows), BK=32, 4 waves 2Mx2N,
// acc 64 AGPR -> 3 blocks/CU (12 waves/CU, was 8). 3-ring, counted vmcnt.
__launch_bounds__(256, 3)
__global__ void k_ffn1(const unsigned short* __restrict__ xb,
                       const unsigned short* __restrict__ Wt,
                       const unsigned short* __restrict__ Vt,
                       const int* __restrict__ perm, const float* __restrict__ pw,
                       const int* __restrict__ ctrl, const int* __restrict__ tileE,
                       const int* __restrict__ tileRow,
                       unsigned short* __restrict__ h) {
  int ti = blockIdx.y;
  if (ti >= ctrl[17]) return;
  int e = tileE[ti];
  int row0 = tileRow[ti];
  int last = ctrl[8 + e] + ctrl[e] - 1;
  int f0 = blockIdx.x * 64;

  __shared__ __align__(16) short As[3][128 * 32];   // 8 KB per buf
  __shared__ __align__(16) short Bs[3][128 * 32];   // 8 KB per buf

  int tid = threadIdx.x;
  int lane = tid & 63, wid = tid >> 6;
  int wr = wid >> 1, wc = wid & 1;

  int sl = (((tid & 3) ^ ((tid >> 3) & 3))) * 8;

  int ar1 = row0 + (tid >> 2); if (ar1 > last) ar1 = last;
  int ar2 = row0 + (tid >> 2) + 64; if (ar2 > last) ar2 = last;
  const unsigned short* agp1 = xb + (size_t)perm[ar1] * DD + sl;
  const unsigned short* agp2 = xb + (size_t)perm[ar2] * DD + sl;
  const unsigned short* wgp = Wt + ((size_t)e * FF + f0 + (tid >> 2)) * DD + sl;
  const unsigned short* vgp = Vt + ((size_t)e * FF + f0 + (tid >> 2)) * DD + sl;

#define STAGE1(buf, k0) do { \
    gload16(agp1 + (k0), &As[buf][tid * 8]); \
    gload16(agp2 + (k0), &As[buf][(tid + 256) * 8]); \
    gload16(wgp + (k0), &Bs[buf][tid * 8]); \
    gload16(vgp + (k0), &Bs[buf][(tid + 256) * 8]); \
  } while (0)

  f32x4 zz = {0.f, 0.f, 0.f, 0.f};
  f32x4 accw[4][2], accv[4][2];
#pragma unroll
  for (int m = 0; m < 4; m++)
#pragma unroll
    for (int n = 0; n < 2; n++) { accw[m][n] = zz; accv[m][n] = zz; }

  int lrow = lane & 15;
  int jx = (((lane >> 4) ^ ((lane >> 1) & 3))) * 8;

#define COMP1(buf) do { \
    bf16x8 a[4], bw[2], bv[2]; \
    _Pragma("unroll") \
    for (int m = 0; m < 4; m++) a[m] = *(bf16x8*)&As[buf][(wr * 64 + m * 16 + lrow) * 32 + jx]; \
    _Pragma("unroll") \
    for (int n = 0; n < 2; n++) { \
      bw[n] = *(bf16x8*)&Bs[buf][(wc * 32 + n * 16 + lrow) * 32 + jx]; \
      bv[n] = *(bf16x8*)&Bs[buf][(64 + wc * 32 + n * 16 + lrow) * 32 + jx]; \
    } \
    _Pragma("unroll") \
    for (int m = 0; m < 4; m++) \
      _Pragma("unroll") \
      for (int n = 0; n < 2; n++) { \
        accw[m][n] = __builtin_amdgcn_mfma_f32_16x16x32_bf16(a[m], bw[n], accw[m][n], 0, 0, 0); \
        accv[m][n] = __builtin_amdgcn_mfma_f32_16x16x32_bf16(a[m], bv[n], accv[m][n], 0, 0, 0); \
      } \
  } while (0)

  // prologue: fill the 3-deep ring (12 loads in flight)
  STAGE1(0, 0); STAGE1(1, 32); STAGE1(2, 64);
#pragma unroll 1
  for (int kt = 0; kt < 4; kt++) {   // ks = 0..11, stages k3..k14
    VMCNT8; BARX; COMP1(0); BARX; STAGE1(0, (kt * 3 + 3) * 32);
    VMCNT8; BARX; COMP1(1); BARX; STAGE1(1, (kt * 3 + 4) * 32);
    VMCNT8; BARX; COMP1(2); BARX; STAGE1(2, (kt * 3 + 5) * 32);
  }
  VMCNT8; BARX; COMP1(0); BARX; STAGE1(0, 15 * 32);  // ks=12, stages k15
  VMCNT8; BARX; COMP1(1);                            // ks=13
  VMCNT4; BARX; COMP1(2);                            // ks=14
  VMCNT0; BARX; COMP1(0);                            // ks=15
#undef STAGE1
#undef COMP1

#pragma unroll
  for (int m = 0; m < 4; m++) {
    int rbase = row0 + wr * 64 + m * 16 + (lane >> 4) * 4;
#pragma unroll
    for (int reg = 0; reg < 4; reg++) {
      int r = rbase + reg;
      if (r > last) continue;
      float pwv = pw[r];
      size_t hrow = (size_t)r * FF;
#pragma unroll
      for (int n = 0; n < 2; n++) {
        float a = accw[m][n][reg];
        float b = accv[m][n][reg];
        float hv = a / (1.f + __expf(-a)) * b * pwv;
        h[hrow + f0 + wc * 32 + n * 16 + lrow] = f2b(hv);
      }
    }
  }
}

// ---------------- GEMM2: yp[pos][d] = h[pos] @ W2t[e]  (bf16 out) -----------
// 128x128 tile, BK=32 over K=F=2048, 4 waves 2x2, acc[4][4], 2-stage dbuf.
__launch_bounds__(256)
__global__ void k_ffn2(const unsigned short* __restrict__ h,
                       const unsigned short* __restrict__ W2t,
                       const int* __restrict__ ctrl,
                       const int* __restrict__ tileE, const int* __restrict__ tileRow,
                       unsigned short* __restrict__ yp) {
  int ti = blockIdx.y;
  if (ti >= ctrl[17]) return;
  int e = tileE[ti];
  int row0 = tileRow[ti];
  int last = ctrl[8 + e] + ctrl[e] - 1;
  int d0 = blockIdx.x * 128;

  __shared__ __align__(16) short As[2][128 * 32];
  __shared__ __align__(16) short Bs[2][128 * 32];

  int tid = threadIdx.x;
  int lane = tid & 63, wid = tid >> 6;
  int wm = (wid >> 1) * 64, wn = (wid & 1) * 64;

  int sl = (((tid & 3) ^ ((tid >> 3) & 3))) * 8;

  int ar1 = row0 + (tid >> 2); if (ar1 > last) ar1 = last;
  int ar2 = row0 + (tid >> 2) + 64; if (ar2 > last) ar2 = last;
  const unsigned short* agp1 = h + (size_t)ar1 * FF + sl;
  const unsigned short* agp2 = h + (size_t)ar2 * FF + sl;
  const unsigned short* bgp1 = W2t + ((size_t)e * DD + d0 + (tid >> 2)) * FF + sl;
  const unsigned short* bgp2 = bgp1 + (size_t)64 * FF;

#define STAGE2(buf, k0) do { \
    gload16(agp1 + (k0), &As[buf][tid * 8]); \
    gload16(agp2 + (k0), &As[buf][(tid + 256) * 8]); \
    gload16(bgp1 + (k0), &Bs[buf][tid * 8]); \
    gload16(bgp2 + (k0), &Bs[buf][(tid + 256) * 8]); \
  } while (0)

  f32x4 zz = {0.f, 0.f, 0.f, 0.f};
  f32x4 acc[4][4];
#pragma unroll
  for (int m = 0; m < 4; m++)
#pragma unroll
    for (int n = 0; n < 4; n++) acc[m][n] = zz;

  int lrow = lane & 15;
  int jx = (((lane >> 4) ^ ((lane >> 1) & 3))) * 8;

#define COMP2(buf) do { \
    bf16x8 a[4], b[4]; \
    _Pragma("unroll") \
    for (int m = 0; m < 4; m++) a[m] = *(bf16x8*)&As[buf][(wm + m * 16 + lrow) * 32 + jx]; \
    _Pragma("unroll") \
    for (int n = 0; n < 4; n++) b[n] = *(bf16x8*)&Bs[buf][(wn + n * 16 + lrow) * 32 + jx]; \
    _Pragma("unroll") \
    for (int m = 0; m < 4; m++) \
      _Pragma("unroll") \
      for (int n = 0; n < 4; n++) \
        acc[m][n] = __builtin_amdgcn_mfma_f32_16x16x32_bf16(a[m], b[n], acc[m][n], 0, 0, 0); \
  } while (0)

  STAGE2(0, 0);
  __syncthreads();
#pragma unroll 1
  for (int ks = 0; ks < 64; ks += 2) {
    if (ks + 1 < 64) STAGE2(1, (ks + 1) * 32);
    COMP2(0);
    __syncthreads();
    if (ks + 2 < 64) STAGE2(0, (ks + 2) * 32);
    COMP2(1);
    __syncthreads();
  }
#undef STAGE2
#undef COMP2

#pragma unroll
  for (int m = 0; m < 4; m++) {
    int rbase = row0 + wm + m * 16 + (lane >> 4) * 4;
#pragma unroll
    for (int reg = 0; reg < 4; reg++) {
      int r = rbase + reg;
      if (r > last) continue;
      unsigned short* ypr = yp + (size_t)r * DD + d0;
#pragma unroll
      for (int n = 0; n < 4; n++)
        ypr[wn + n * 16 + lrow] = f2b(acc[m][n][reg]);
    }
  }
}

// ---------------- gather: y[t] = yp[inv[2t]] + yp[inv[2t+1]]  (bf16 in) -----
__launch_bounds__(256)
__global__ void k_gather(const unsigned short* __restrict__ yp,
                         const int* __restrict__ inv, float* __restrict__ y) {
  int i = blockIdx.x * 256 + threadIdx.x;   // over TT*64 groups of 8 cols
  int t = i >> 6, seg = (i & 63) * 8;
  int pa = inv[2 * t], pb = inv[2 * t + 1];
  bf16x8 a = *(const bf16x8*)(yp + (size_t)pa * DD + seg);
  bf16x8 b = *(const bf16x8*)(yp + (size_t)pb * DD + seg);
  float* yr = y + (size_t)t * DD + seg;
  float4 o0, o1;
  o0.x = b2f((unsigned short)a[0]) + b2f((unsigned short)b[0]);
  o0.y = b2f((unsigned short)a[1]) + b2f((unsigned short)b[1]);
  o0.z = b2f((unsigned short)a[2]) + b2f((unsigned short)b[2]);
  o0.w = b2f((unsigned short)a[3]) + b2f((unsigned short)b[3]);
  o1.x = b2f((unsigned short)a[4]) + b2f((unsigned short)b[4]);
  o1.y = b2f((unsigned short)a[5]) + b2f((unsigned short)b[5]);
  o1.z = b2f((unsigned short)a[6]) + b2f((unsigned short)b[6]);
  o1.w = b2f((unsigned short)a[7]) + b2f((unsigned short)b[7]);
  *(float4*)yr = o0;
  *(float4*)(yr + 4) = o1;
}

extern "C" void kernel_launch(void* const* d_in, const int* in_sizes, int n_in,
                              void* d_out, int out_size, void* d_ws, size_t ws_size,
                              hipStream_t stream) {
  const float* x  = (const float*)d_in[0];
  const float* Wg = (const float*)d_in[1];
  const float* W  = (const float*)d_in[2];
  const float* V  = (const float*)d_in[3];
  const float* W2 = (const float*)d_in[4];
  float* y = (float*)d_out;

  char* ws = (char*)d_ws;
  size_t off = 0;
  auto alloc = [&](size_t n) -> char* {
    char* p = ws + off;
    off += (n + 255) & ~(size_t)255;
    return p;
  };
  unsigned short* xb  = (unsigned short*)alloc((size_t)TT * DD * 2);
  unsigned short* Wt  = (unsigned short*)alloc((size_t)EE * DD * FF * 2);
  unsigned short* Vt  = (unsigned short*)alloc((size_t)EE * DD * FF * 2);
  unsigned short* W2t = (unsigned short*)alloc((size_t)EE * DD * FF * 2);
  unsigned short* h   = (unsigned short*)alloc((size_t)TT * 2 * FF * 2);
  int*   perm = (int*)alloc(TT * 2 * 4);
  float* pw   = (float*)alloc(TT * 2 * 4);
  int*   te   = (int*)alloc(TT * 2 * 4);
  float* tw   = (float*)alloc(TT * 2 * 4);
  int*   inv  = (int*)alloc(TT * 2 * 4);
  int*   ctrl = (int*)alloc(256);
  int*   tileE   = (int*)alloc(MAXT * 4);
  int*   tileRow = (int*)alloc(MAXT * 4);
  if (off > ws_size) return;

  // yp (16384x512 bf16 = 16.8 MB) aliases Wt (dead after ffn1).
  unsigned short* yp = (unsigned short*)Wt;

  k_prep<<<TT / 4, 256, 0, stream>>>(x, Wg, xb, te, tw);
  k_tcvt_all<<<dim3(1024, 24), dim3(32, 8), 0, stream>>>(W, V, W2, Wt, Vt, W2t);
  k_route<<<1, 1024, 0, stream>>>(te, tw, ctrl, perm, pw, tileE, tileRow, inv);
  k_ffn1<<<dim3(FF / 64, MAXT), 256, 0, stream>>>(xb, Wt, Vt, perm, pw, ctrl, tileE, tileRow, h);
  k_ffn2<<<dim3(DD / 128, MAXT), 256, 0, stream>>>(h, W2t, ctrl, tileE, tileRow, yp);
  k_gather<<<TT * 64 / 256, 256, 0, stream>>>(yp, inv, y);
}

// Round 17
// 235.784 us; speedup vs baseline: 1.0237x; 1.0237x over previous
//
#include <hip/hip_runtime.h>
#include <hip/hip_bf16.h>
#include <stdint.h>

// MoE: B=4,S=2048,D=512,F=2048,E=8,K=2.  T = B*S = 8192 tokens.
#define TT 8192
#define DD 512
#define FF 2048
#define EE 8
#define MAXT 136   // max row-tiles at BM=128

typedef __attribute__((ext_vector_type(8))) short bf16x8;
typedef __attribute__((ext_vector_type(4))) float f32x4;

static __device__ __forceinline__ unsigned short f2b(float f) {
  union { __hip_bfloat16 b; unsigned short u; } cv;
  cv.b = __float2bfloat16(f);
  return cv.u;
}
static __device__ __forceinline__ float b2f(unsigned short u) {
  union { unsigned int i; float f; } cv;
  cv.i = ((unsigned int)u) << 16;
  return cv.f;
}

// async global->LDS, 16B per lane. LDS dest must be wave_base + lane*16.
static __device__ __forceinline__ void gload16(const void* g, void* l) {
  __builtin_amdgcn_global_load_lds(
      (const __attribute__((address_space(1))) unsigned int*)g,
      (__attribute__((address_space(3))) unsigned int*)l, 16, 0, 0);
}

#define VMCNT12 asm volatile("s_waitcnt vmcnt(12)" ::: "memory")
#define VMCNT6  asm volatile("s_waitcnt vmcnt(6)" ::: "memory")
#define VMCNT0  asm volatile("s_waitcnt vmcnt(0)" ::: "memory")
#define BARX    asm volatile("s_barrier" ::: "memory")

// ---------------- prep: gate logits (fp32) + x->bf16 --------------------
__launch_bounds__(256)
__global__ void k_prep(const float* __restrict__ x, const float* __restrict__ Wg,
                       unsigned short* __restrict__ xb,
                       int* __restrict__ te, float* __restrict__ tw) {
  int wid = threadIdx.x >> 6, lane = threadIdx.x & 63;
  int t = blockIdx.x * 4 + wid;
  const float* xr = x + (size_t)t * DD;
  unsigned short* xbr = xb + (size_t)t * DD;
  int d0 = lane * 8;

  float4 v0 = *(const float4*)(xr + d0);
  float4 v1 = *(const float4*)(xr + d0 + 4);
  ushort4 o0, o1;
  o0.x = f2b(v0.x); o0.y = f2b(v0.y); o0.z = f2b(v0.z); o0.w = f2b(v0.w);
  o1.x = f2b(v1.x); o1.y = f2b(v1.y); o1.z = f2b(v1.z); o1.w = f2b(v1.w);
  *(ushort4*)(xbr + d0) = o0;
  *(ushort4*)(xbr + d0 + 4) = o1;

  float xv[8] = {v0.x, v0.y, v0.z, v0.w, v1.x, v1.y, v1.z, v1.w};
  float acc[EE];
#pragma unroll
  for (int e = 0; e < EE; e++) acc[e] = 0.f;
#pragma unroll
  for (int j = 0; j < 8; j++) {
    const float* wg = Wg + (size_t)(d0 + j) * EE;
    float4 a = *(const float4*)wg;
    float4 b = *(const float4*)(wg + 4);
    acc[0] += xv[j] * a.x; acc[1] += xv[j] * a.y; acc[2] += xv[j] * a.z; acc[3] += xv[j] * a.w;
    acc[4] += xv[j] * b.x; acc[5] += xv[j] * b.y; acc[6] += xv[j] * b.z; acc[7] += xv[j] * b.w;
  }
#pragma unroll
  for (int e = 0; e < EE; e++)
    for (int o = 32; o; o >>= 1) acc[e] += __shfl_xor(acc[e], o);
  if (lane == 0) {
    int e1 = 0; float v1m = acc[0];
#pragma unroll
    for (int e = 1; e < EE; e++) if (acc[e] > v1m) { v1m = acc[e]; e1 = e; }
    int e2 = -1; float v2m = -INFINITY;
#pragma unroll
    for (int e = 0; e < EE; e++) if (e != e1 && acc[e] > v2m) { v2m = acc[e]; e2 = e; }
    float ex = __expf(v2m - v1m);
    float w1 = 1.f / (1.f + ex);
    float w2 = ex / (1.f + ex);
    te[t * 2] = e1; te[t * 2 + 1] = e2;
    tw[t * 2] = w1; tw[t * 2 + 1] = w2;
  }
}

// ------------- transpose+convert, 64x64 tiles, vectorized 16B stores --------
// z<16: W/V [DD][FF] -> [FF][DD]; z>=16: W2 [FF][DD] -> [DD][FF].
__launch_bounds__(256)
__global__ void k_tcvt_all(const float* __restrict__ W, const float* __restrict__ V,
                           const float* __restrict__ W2, unsigned short* __restrict__ Wt,
                           unsigned short* __restrict__ Vt, unsigned short* __restrict__ W2t) {
  __shared__ float tile[64][65];
  int z = blockIdx.y;
  const float* src; unsigned short* dst; int M, N;
  if (z < 16) {
    int e = z & 7;
    size_t base = (size_t)e * DD * FF;
    src = (z < 8 ? W : V) + base;
    dst = (z < 8 ? Wt : Vt) + base;
    M = DD; N = FF;
  } else {
    int e = z - 16;
    size_t base = (size_t)e * DD * FF;
    src = W2 + base; dst = W2t + base;
    M = FF; N = DD;
  }
  int nbx = N >> 6;
  int bx = blockIdx.x;
  int cb = (bx % nbx) * 64, rb = (bx / nbx) * 64;
  int t = threadIdx.x;
#pragma unroll
  for (int i = 0; i < 4; i++) {
    int idx = i * 256 + t;
    int r = idx >> 4, cblk = (idx & 15) * 4;
    float4 v = *(const float4*)(src + (size_t)(rb + r) * N + cb + cblk);
    tile[r][cblk] = v.x; tile[r][cblk + 1] = v.y;
    tile[r][cblk + 2] = v.z; tile[r][cblk + 3] = v.w;
  }
  __syncthreads();
#pragma unroll
  for (int j = 0; j < 2; j++) {
    int idx = j * 256 + t;
    int c = idx >> 3, seg = (idx & 7) * 8;
    bf16x8 o;
#pragma unroll
    for (int k = 0; k < 8; k++) o[k] = (short)f2b(tile[seg + k][c]);
    *(bf16x8*)(dst + (size_t)(cb + c) * M + rb + seg) = o;
  }
}

// ---------------- routing: single-block deterministic counting sort --------
__launch_bounds__(1024)
__global__ void k_route(const int* __restrict__ te, const float* __restrict__ tw,
                        int* __restrict__ ctrl, int* __restrict__ perm,
                        float* __restrict__ pw, int* __restrict__ tileE,
                        int* __restrict__ tileRow, int* __restrict__ inv) {
  __shared__ int wsum[17][EE];
  __shared__ int ebase[EE];
  int tid = threadIdx.x;
  int lane = tid & 63, wid = tid >> 6;
  int myte[16]; float mytw[16];
  int c[EE];
#pragma unroll
  for (int e = 0; e < EE; e++) c[e] = 0;
  int s0 = tid * 16;
#pragma unroll
  for (int j = 0; j < 16; j++) {
    myte[j] = te[s0 + j];
    mytw[j] = tw[s0 + j];
#pragma unroll
    for (int e = 0; e < EE; e++) if (myte[j] == e) c[e]++;
  }
  int incl[EE];
#pragma unroll
  for (int e = 0; e < EE; e++) incl[e] = c[e];
  for (int off = 1; off < 64; off <<= 1) {
#pragma unroll
    for (int e = 0; e < EE; e++) {
      int v = __shfl_up(incl[e], off);
      if (lane >= off) incl[e] += v;
    }
  }
  if (lane == 63)
#pragma unroll
    for (int e = 0; e < EE; e++) wsum[wid][e] = incl[e];
  __syncthreads();
  if (tid < EE) {
    int s = 0;
    for (int w = 0; w < 16; w++) { int v = wsum[w][tid]; wsum[w][tid] = s; s += v; }
    wsum[16][tid] = s;
  }
  __syncthreads();
  if (tid == 0) {
    int s = 0, nt = 0;
    for (int e = 0; e < EE; e++) {
      int cnt = wsum[16][e];
      ebase[e] = s; ctrl[8 + e] = s; ctrl[e] = cnt;
      for (int i = 0; i < cnt; i += 128) { tileE[nt] = e; tileRow[nt] = s + i; nt++; }
      s += cnt;
    }
    ctrl[16] = s; ctrl[17] = nt;
  }
  __syncthreads();
#pragma unroll
  for (int e = 0; e < EE; e++) {
    int p = ebase[e] + wsum[wid][e] + incl[e] - c[e];
#pragma unroll
    for (int j = 0; j < 16; j++) {
      if (myte[j] == e) {
        perm[p] = (s0 + j) >> 1;
        pw[p] = mytw[j];
        inv[s0 + j] = p;
        p++;
      }
    }
  }
}

// ---------------- GEMM1: h[pos][f] = pw * silu(x@W) * (x@V) -----------------
// BM=128 rows x 128 F-cols (W and V -> 256 LDS B-rows), BK=32, 4 waves 2Mx2N.
// 3-buffer ring, 2-step lookahead, counted vmcnt, raw s_barrier. (round-11)
__launch_bounds__(256, 2)
__global__ void k_ffn1(const unsigned short* __restrict__ xb,
                       const unsigned short* __restrict__ Wt,
                       const unsigned short* __restrict__ Vt,
                       const int* __restrict__ perm, const float* __restrict__ pw,
                       const int* __restrict__ ctrl, const int* __restrict__ tileE,
                       const int* __restrict__ tileRow,
                       unsigned short* __restrict__ h) {
  int ti = blockIdx.y;
  if (ti >= ctrl[17]) return;
  int e = tileE[ti];
  int row0 = tileRow[ti];
  int last = ctrl[8 + e] + ctrl[e] - 1;
  int f0 = blockIdx.x * 128;

  __shared__ __align__(16) short As[3][128 * 32];   // 8 KB per buf
  __shared__ __align__(16) short Bs[3][256 * 32];   // 16 KB per buf

  int tid = threadIdx.x;
  int lane = tid & 63, wid = tid >> 6;
  int wr = wid >> 1, wc = wid & 1;

  int sl = (((tid & 3) ^ ((tid >> 3) & 3))) * 8;

  int ar1 = row0 + (tid >> 2); if (ar1 > last) ar1 = last;
  int ar2 = row0 + (tid >> 2) + 64; if (ar2 > last) ar2 = last;
  const unsigned short* agp1 = xb + (size_t)perm[ar1] * DD + sl;
  const unsigned short* agp2 = xb + (size_t)perm[ar2] * DD + sl;
  const unsigned short* wgp1 = Wt + ((size_t)e * FF + f0 + (tid >> 2)) * DD + sl;
  const unsigned short* wgp2 = wgp1 + (size_t)64 * DD;
  const unsigned short* vgp1 = Vt + ((size_t)e * FF + f0 + (tid >> 2)) * DD + sl;
  const unsigned short* vgp2 = vgp1 + (size_t)64 * DD;

#define STAGE1(buf, k0) do { \
    gload16(agp1 + (k0), &As[buf][tid * 8]); \
    gload16(agp2 + (k0), &As[buf][(tid + 256) * 8]); \
    gload16(wgp1 + (k0), &Bs[buf][tid * 8]); \
    gload16(wgp2 + (k0), &Bs[buf][(tid + 256) * 8]); \
    gload16(vgp1 + (k0), &Bs[buf][(tid + 512) * 8]); \
    gload16(vgp2 + (k0), &Bs[buf][(tid + 768) * 8]); \
  } while (0)

  f32x4 zz = {0.f, 0.f, 0.f, 0.f};
  f32x4 accw[4][4], accv[4][4];
#pragma unroll
  for (int m = 0; m < 4; m++)
#pragma unroll
    for (int n = 0; n < 4; n++) { accw[m][n] = zz; accv[m][n] = zz; }

  int lrow = lane & 15;
  int jx = (((lane >> 4) ^ ((lane >> 1) & 3))) * 8;

#define COMP1(buf) do { \
    bf16x8 a[4], bw[4], bv[4]; \
    _Pragma("unroll") \
    for (int m = 0; m < 4; m++) a[m] = *(bf16x8*)&As[buf][(wr * 64 + m * 16 + lrow) * 32 + jx]; \
    _Pragma("unroll") \
    for (int n = 0; n < 4; n++) { \
      bw[n] = *(bf16x8*)&Bs[buf][(wc * 64 + n * 16 + lrow) * 32 + jx]; \
      bv[n] = *(bf16x8*)&Bs[buf][(128 + wc * 64 + n * 16 + lrow) * 32 + jx]; \
    } \
    _Pragma("unroll") \
    for (int m = 0; m < 4; m++) \
      _Pragma("unroll") \
      for (int n = 0; n < 4; n++) { \
        accw[m][n] = __builtin_amdgcn_mfma_f32_16x16x32_bf16(a[m], bw[n], accw[m][n], 0, 0, 0); \
        accv[m][n] = __builtin_amdgcn_mfma_f32_16x16x32_bf16(a[m], bv[n], accv[m][n], 0, 0, 0); \
      } \
  } while (0)

  // prologue: fill the 3-deep ring (18 loads in flight)
  STAGE1(0, 0); STAGE1(1, 32); STAGE1(2, 64);
#pragma unroll 1
  for (int kt = 0; kt < 4; kt++) {   // ks = 0..11, stages k3..k14
    VMCNT12; BARX; COMP1(0); BARX; STAGE1(0, (kt * 3 + 3) * 32);
    VMCNT12; BARX; COMP1(1); BARX; STAGE1(1, (kt * 3 + 4) * 32);
    VMCNT12; BARX; COMP1(2); BARX; STAGE1(2, (kt * 3 + 5) * 32);
  }
  VMCNT12; BARX; COMP1(0); BARX; STAGE1(0, 15 * 32);  // ks=12, stages k15
  VMCNT12; BARX; COMP1(1);                            // ks=13
  VMCNT6;  BARX; COMP1(2);                            // ks=14
  VMCNT0;  BARX; COMP1(0);                            // ks=15
#undef STAGE1
#undef COMP1

#pragma unroll
  for (int m = 0; m < 4; m++) {
    int rbase = row0 + wr * 64 + m * 16 + (lane >> 4) * 4;
#pragma unroll
    for (int reg = 0; reg < 4; reg++) {
      int r = rbase + reg;
      if (r > last) continue;
      float pwv = pw[r];
      size_t hrow = (size_t)r * FF;
#pragma unroll
      for (int n = 0; n < 4; n++) {
        float a = accw[m][n][reg];
        float b = accv[m][n][reg];
        float hv = a / (1.f + __expf(-a)) * b * pwv;
        h[hrow + f0 + wc * 64 + n * 16 + lrow] = f2b(hv);
      }
    }
  }
}

// ---------------- GEMM2: yp[pos][d] = h[pos] @ W2t[e]  (bf16 out) -----------
// 128x128 tile, BK=32 over K=F=2048, 4 waves 2x2, acc[4][4], 2-stage dbuf.
__launch_bounds__(256)
__global__ void k_ffn2(const unsigned short* __restrict__ h,
                       const unsigned short* __restrict__ W2t,
                       const int* __restrict__ ctrl,
                       const int* __restrict__ tileE, const int* __restrict__ tileRow,
                       unsigned short* __restrict__ yp) {
  int ti = blockIdx.y;
  if (ti >= ctrl[17]) return;
  int e = tileE[ti];
  int row0 = tileRow[ti];
  int last = ctrl[8 + e] + ctrl[e] - 1;
  int d0 = blockIdx.x * 128;

  __shared__ __align__(16) short As[2][128 * 32];
  __shared__ __align__(16) short Bs[2][128 * 32];

  int tid = threadIdx.x;
  int lane = tid & 63, wid = tid >> 6;
  int wm = (wid >> 1) * 64, wn = (wid & 1) * 64;

  int sl = (((tid & 3) ^ ((tid >> 3) & 3))) * 8;

  int ar1 = row0 + (tid >> 2); if (ar1 > last) ar1 = last;
  int ar2 = row0 + (tid >> 2) + 64; if (ar2 > last) ar2 = last;
  const unsigned short* agp1 = h + (size_t)ar1 * FF + sl;
  const unsigned short* agp2 = h + (size_t)ar2 * FF + sl;
  const unsigned short* bgp1 = W2t + ((size_t)e * DD + d0 + (tid >> 2)) * FF + sl;
  const unsigned short* bgp2 = bgp1 + (size_t)64 * FF;

#define STAGE2(buf, k0) do { \
    gload16(agp1 + (k0), &As[buf][tid * 8]); \
    gload16(agp2 + (k0), &As[buf][(tid + 256) * 8]); \
    gload16(bgp1 + (k0), &Bs[buf][tid * 8]); \
    gload16(bgp2 + (k0), &Bs[buf][(tid + 256) * 8]); \
  } while (0)

  f32x4 zz = {0.f, 0.f, 0.f, 0.f};
  f32x4 acc[4][4];
#pragma unroll
  for (int m = 0; m < 4; m++)
#pragma unroll
    for (int n = 0; n < 4; n++) acc[m][n] = zz;

  int lrow = lane & 15;
  int jx = (((lane >> 4) ^ ((lane >> 1) & 3))) * 8;

#define COMP2(buf) do { \
    bf16x8 a[4], b[4]; \
    _Pragma("unroll") \
    for (int m = 0; m < 4; m++) a[m] = *(bf16x8*)&As[buf][(wm + m * 16 + lrow) * 32 + jx]; \
    _Pragma("unroll") \
    for (int n = 0; n < 4; n++) b[n] = *(bf16x8*)&Bs[buf][(wn + n * 16 + lrow) * 32 + jx]; \
    _Pragma("unroll") \
    for (int m = 0; m < 4; m++) \
      _Pragma("unroll") \
      for (int n = 0; n < 4; n++) \
        acc[m][n] = __builtin_amdgcn_mfma_f32_16x16x32_bf16(a[m], b[n], acc[m][n], 0, 0, 0); \
  } while (0)

  STAGE2(0, 0);
  __syncthreads();
#pragma unroll 1
  for (int ks = 0; ks < 64; ks += 2) {
    if (ks + 1 < 64) STAGE2(1, (ks + 1) * 32);
    COMP2(0);
    __syncthreads();
    if (ks + 2 < 64) STAGE2(0, (ks + 2) * 32);
    COMP2(1);
    __syncthreads();
  }
#undef STAGE2
#undef COMP2

#pragma unroll
  for (int m = 0; m < 4; m++) {
    int rbase = row0 + wm + m * 16 + (lane >> 4) * 4;
#pragma unroll
    for (int reg = 0; reg < 4; reg++) {
      int r = rbase + reg;
      if (r > last) continue;
      unsigned short* ypr = yp + (size_t)r * DD + d0;
#pragma unroll
      for (int n = 0; n < 4; n++)
        ypr[wn + n * 16 + lrow] = f2b(acc[m][n][reg]);
    }
  }
}

// ---------------- gather: y[t] = yp[inv[2t]] + yp[inv[2t+1]]  (bf16 in) -----
__launch_bounds__(256)
__global__ void k_gather(const unsigned short* __restrict__ yp,
                         const int* __restrict__ inv, float* __restrict__ y) {
  int i = blockIdx.x * 256 + threadIdx.x;   // over TT*64 groups of 8 cols
  int t = i >> 6, seg = (i & 63) * 8;
  int pa = inv[2 * t], pb = inv[2 * t + 1];
  bf16x8 a = *(const bf16x8*)(yp + (size_t)pa * DD + seg);
  bf16x8 b = *(const bf16x8*)(yp + (size_t)pb * DD + seg);
  float* yr = y + (size_t)t * DD + seg;
  float4 o0, o1;
  o0.x = b2f((unsigned short)a[0]) + b2f((unsigned short)b[0]);
  o0.y = b2f((unsigned short)a[1]) + b2f((unsigned short)b[1]);
  o0.z = b2f((unsigned short)a[2]) + b2f((unsigned short)b[2]);
  o0.w = b2f((unsigned short)a[3]) + b2f((unsigned short)b[3]);
  o1.x = b2f((unsigned short)a[4]) + b2f((unsigned short)b[4]);
  o1.y = b2f((unsigned short)a[5]) + b2f((unsigned short)b[5]);
  o1.z = b2f((unsigned short)a[6]) + b2f((unsigned short)b[6]);
  o1.w = b2f((unsigned short)a[7]) + b2f((unsigned short)b[7]);
  *(float4*)yr = o0;
  *(float4*)(yr + 4) = o1;
}

extern "C" void kernel_launch(void* const* d_in, const int* in_sizes, int n_in,
                              void* d_out, int out_size, void* d_ws, size_t ws_size,
                              hipStream_t stream) {
  const float* x  = (const float*)d_in[0];
  const float* Wg = (const float*)d_in[1];
  const float* W  = (const float*)d_in[2];
  const float* V  = (const float*)d_in[3];
  const float* W2 = (const float*)d_in[4];
  float* y = (float*)d_out;

  char* ws = (char*)d_ws;
  size_t off = 0;
  auto alloc = [&](size_t n) -> char* {
    char* p = ws + off;
    off += (n + 255) & ~(size_t)255;
    return p;
  };
  unsigned short* xb  = (unsigned short*)alloc((size_t)TT * DD * 2);
  unsigned short* Wt  = (unsigned short*)alloc((size_t)EE * DD * FF * 2);
  unsigned short* Vt  = (unsigned short*)alloc((size_t)EE * DD * FF * 2);
  unsigned short* W2t = (unsigned short*)alloc((size_t)EE * DD * FF * 2);
  unsigned short* h   = (unsigned short*)alloc((size_t)TT * 2 * FF * 2);
  int*   perm = (int*)alloc(TT * 2 * 4);
  float* pw   = (float*)alloc(TT * 2 * 4);
  int*   te   = (int*)alloc(TT * 2 * 4);
  float* tw   = (float*)alloc(TT * 2 * 4);
  int*   inv  = (int*)alloc(TT * 2 * 4);
  int*   ctrl = (int*)alloc(256);
  int*   tileE   = (int*)alloc(MAXT * 4);
  int*   tileRow = (int*)alloc(MAXT * 4);
  if (off > ws_size) return;

  // yp (16384x512 bf16 = 16.8 MB) aliases Wt (dead after ffn1).
  unsigned short* yp = (unsigned short*)Wt;

  k_prep<<<TT / 4, 256, 0, stream>>>(x, Wg, xb, te, tw);
  k_tcvt_all<<<dim3(256, 24), 256, 0, stream>>>(W, V, W2, Wt, Vt, W2t);
  k_route<<<1, 1024, 0, stream>>>(te, tw, ctrl, perm, pw, tileE, tileRow, inv);
  k_ffn1<<<dim3(FF / 128, MAXT), 256, 0, stream>>>(xb, Wt, Vt, perm, pw, ctrl, tileE, tileRow, h);
  k_ffn2<<<dim3(DD / 128, MAXT), 256, 0, stream>>>(h, W2t, ctrl, tileE, tileRow, yp);
  k_gather<<<TT * 64 / 256, 256, 0, stream>>>(yp, inv, y);
}